// Round 6
// baseline (239.376 us; speedup 1.0000x reference)
//
#include <hip/hip_runtime.h>
#include <hip/hip_bf16.h>

// CausalAttentionModule: B=4, C=64, H=W=64, NH=8, hd=8, BL=5, BS=25, MASK_ONES=12
// Round 6 = round 5 with the workspace-overlap bug fixed:
// qkvh is 16384*192 f16 = 1,572,864 FLOATS (round 5 placed osT at +786432 -> overlap -> NaN).

typedef _Float16 h2f __attribute__((ext_vector_type(2)));
typedef _Float16 h8  __attribute__((ext_vector_type(8)));
union u8h { h8 v; h2f p[4]; };
union pk4 { _Float16 h[4]; unsigned int u[2]; };

__device__ __forceinline__ float fdot2f(h2f a, h2f b, float c) {
#if defined(__has_builtin)
#if __has_builtin(__builtin_amdgcn_fdot2)
    return __builtin_amdgcn_fdot2(a, b, c, false);
#else
    return c + (float)a.x*(float)b.x + (float)a.y*(float)b.y;
#endif
#else
    return c + (float)a.x*(float)b.x + (float)a.y*(float)b.y;
#endif
}
__device__ __forceinline__ float dot8(u8h a, u8h b) {
    float c = 0.f;
    c = fdot2f(a.p[0], b.p[0], c);
    c = fdot2f(a.p[1], b.p[1], c);
    c = fdot2f(a.p[2], b.p[2], c);
    c = fdot2f(a.p[3], b.p[3], c);
    return c;
}
__device__ __forceinline__ float frcp(float x) {
#if defined(__has_builtin)
#if __has_builtin(__builtin_amdgcn_rcpf)
    return __builtin_amdgcn_rcpf(x);
#else
    return 1.0f/x;
#endif
#else
    return 1.0f/x;
#endif
}

#define SC 0.35355339059327373f  // 1/sqrt(8)

// ---------------- K1: LN1+QKV (256) | xsum (256) | wconv (8) | setup (1) ----------------
__global__ __launch_bounds__(1024) void k_qkv(
    const float* __restrict__ x, const float* __restrict__ n1w, const float* __restrict__ n1b,
    const float* __restrict__ qw, const float* __restrict__ qb, const float* __restrict__ rpb,
    const float* __restrict__ w1, const float* __restrict__ w2, const float* __restrict__ pw,
    _Float16* __restrict__ qkvh, _Float16* __restrict__ qkvc_h, _Float16* __restrict__ eb7,
    _Float16* __restrict__ w1h, _Float16* __restrict__ w2h, _Float16* __restrict__ pwh,
    float* __restrict__ osT)
{
    __shared__ float sxp[68*68];
    const int t = threadIdx.x, bid = blockIdx.x;
    if (bid < 256) {
        // main: lane = pixel, wave = output group (wave-uniform weight rows -> s_load)
        const int pix = t & 63, g = t >> 6;
        const int p = bid*64 + pix;
        const int b = p >> 12, hw = p & 4095;
        const float* xp = x + (size_t)b*262144 + hw;
        float xr[64]; float s = 0.f, s2 = 0.f;
        #pragma unroll
        for (int c = 0; c < 64; ++c) { float v = xp[(size_t)c*4096]; xr[c] = v; s += v; s2 += v*v; }
        float m = s*0.015625f;
        float rstd = rsqrtf(fmaxf(s2*0.015625f - m*m, 0.f) + 1e-5f);
        #pragma unroll
        for (int c = 0; c < 64; ++c) xr[c] = (xr[c] - m)*rstd*n1w[c] + n1b[c];
        _Float16* orow = qkvh + (size_t)p*192;
        #pragma unroll
        for (int i4 = 0; i4 < 12; i4 += 4) {
            const int o = g*12 + i4;
            const float* wr = qw + o*64;
            float a0 = qb[o], a1 = qb[o+1], a2 = qb[o+2], a3 = qb[o+3];
            #pragma unroll 16
            for (int c = 0; c < 64; ++c) {
                float xv = xr[c];
                a0 += xv*wr[c]; a1 += xv*wr[64+c]; a2 += xv*wr[128+c]; a3 += xv*wr[192+c];
            }
            pk4 pk;
            pk.h[0]=(_Float16)a0; pk.h[1]=(_Float16)a1; pk.h[2]=(_Float16)a2; pk.h[3]=(_Float16)a3;
            *(uint2*)(orow + o) = make_uint2(pk.u[0], pk.u[1]);
        }
        return;
    }
    if (bid < 512) {
        // xsum over the 12 unmasked (causal raster) neighbors, per (b,c) plane
        const int plane = bid - 256;                 // b*64 + c
        for (int i = t; i < 4624; i += 1024) sxp[i] = 0.f;
        __syncthreads();
        const float* xp = x + (size_t)plane*4096;
        for (int i = t; i < 4096; i += 1024) {
            int r = i >> 6, w = i & 63;
            sxp[(r + 2)*68 + (w + 2)] = xp[i];
        }
        __syncthreads();
        const int c = plane & 63, b = plane >> 6;
        float* op = osT + (size_t)c*16384 + b*4096;
        for (int i = t; i < 4096; i += 1024) {
            int r = i >> 6, w = i & 63;
            const float* s0 = sxp + r*68 + w;
            float sv = s0[0]+s0[1]+s0[2]+s0[3]+s0[4]
                     + s0[68]+s0[69]+s0[70]+s0[71]+s0[72]
                     + s0[136]+s0[137];
            op[i] = sv;
        }
        return;
    }
    if (bid < 520) {
        // f16 weight conversion, spread over 8 blocks
        const int cid = bid - 512;
        for (int i = t; i < 4608; i += 1024) {
            int j = cid*4608 + i;
            if (j < 16384)      w1h[j]          = (_Float16)w1[j];
            else if (j < 32768) w2h[j - 16384]  = (_Float16)w2[j - 16384];
            else                pwh[j - 32768]  = (_Float16)pw[j - 32768];
        }
        return;
    }
    // setup: qkv_const = n1b @ qkv_w^T + qkv_b; 7-slot exp(bias) table
    if (t < 192) {
        float acc = qb[t];
        for (int c = 0; c < 64; ++c) acc += n1b[c]*qw[t*64 + c];
        qkvc_h[t] = (_Float16)acc;
    }
    for (int i = t; i < 3200; i += 1024) {
        int j = i & 7, hf = (i >> 3) & 1, r = i >> 4;   // r = h*25+q
        int h = r/25, q = r - h*25;
        float v = 0.f;
        if (j < 6) {
            int k = hf*6 + j;
            int ridx = (q/5 - k/5 + 4)*9 + (q%5 - k%5 + 4);
            v = __expf(rpb[ridx*8 + h]);
        } else if (j == 6 && hf) {
            for (int k = 12; k < 25; ++k) {
                int ridx = (q/5 - k/5 + 4)*9 + (q%5 - k%5 + 4);
                v += __expf(rpb[ridx*8 + h]);
            }
        }
        eb7[i] = (_Float16)v;
    }
}

// ---------------- K2: attention, k-split halves via shfl_xor(16) ----------------
// block = 256: pix(16) x half(2) x head(8); 1024 blocks of 16 pixels.
// Slot set per half: half0 = k {0..5} + dummy(weight 0); half1 = k {6..11} + const-slot.
__global__ __launch_bounds__(256) void k_attn(
    const _Float16* __restrict__ qkvh, const _Float16* __restrict__ qkvc_h,
    const _Float16* __restrict__ eb7g, float* __restrict__ osT)
{
    __shared__ alignas(16) _Float16 sq[60*200];   // 3 img rows x 20 cols, stride 200 f16
    __shared__ alignas(16) _Float16 seb[3200];    // [h][q][half][8]
    __shared__ alignas(16) _Float16 sqc[192];
    const int t = threadIdx.x;
    const int p0 = blockIdx.x*16;
    const int b = p0 >> 12, hw0 = p0 & 4095, hrow = hw0 >> 6, w0c = hw0 & 63;

    for (int i = t; i < 1600; i += 256) ((unsigned int*)seb)[i] = ((const unsigned int*)eb7g)[i];
    if (t < 96) ((unsigned int*)sqc)[t] = ((const unsigned int*)qkvc_h)[t];
    for (int i = t; i < 1440; i += 256) {
        int row = i/24, d4 = i%24;
        int rr = row/20, cc = row%20;
        int gr = hrow - 2 + rr, gc = w0c - 2 + cc;
        float4 v = (gr >= 0 && gc >= 0 && gc < 64)
            ? ((const float4*)qkvh)[(size_t)((b << 12) + (gr << 6) + gc)*24 + d4]
            : ((const float4*)qkvc_h)[d4];
        *(float4*)(sq + row*200 + d4*8) = v;
    }
    __syncthreads();

    const int pix = t & 15, hf = (t >> 4) & 1, h = t >> 5, hb = h*8;
    int rws[6];
    #pragma unroll
    for (int j = 0; j < 6; ++j) { int k = hf*6 + j; rws[j] = (k/5)*20 + pix + (k%5); }
    u8h kreg[7];
    #pragma unroll
    for (int j = 0; j < 6; ++j) kreg[j].v = *(const h8*)(sq + rws[j]*200 + 64 + hb);
    kreg[6].v = hf ? *(const h8*)(sqc + 64 + hb) : kreg[0].v;
    u8h qcu; qcu.v = *(const h8*)(sqc + hb);
    float edc[7];
    #pragma unroll
    for (int j = 0; j < 7; ++j) edc[j] = __expf(dot8(qcu, kreg[j])*SC);
    float w[7];
    #pragma unroll
    for (int j = 0; j < 7; ++j) w[j] = 0.f;
    const _Float16* ebbase = seb + h*400 + hf*8;

    // 12 real q rows (slots 0..11 of the center pixel's window)
    for (int sIdx = 0; sIdx < 12; ++sIdx) {
        int rq = (sIdx/5)*20 + pix + (sIdx%5);
        u8h qu; qu.v = *(const h8*)(sq + rq*200 + hb);
        h8 eb8 = *(const h8*)(ebbase + sIdx*16);
        float e[7]; float rs = 0.f;
        #pragma unroll
        for (int j = 0; j < 7; ++j) {
            float ev = __expf(dot8(qu, kreg[j])*SC)*(float)eb8[j];
            e[j] = ev; rs += ev;
        }
        rs += __shfl_xor(rs, 16);
        float inv = frcp(rs);
        #pragma unroll
        for (int j = 0; j < 7; ++j) w[j] += e[j]*inv;
    }
    // 13 constant q rows: dots shared (edc), bias row differs
    for (int q = 12; q < 25; ++q) {
        h8 eb8 = *(const h8*)(ebbase + q*16);
        float e[7]; float rs = 0.f;
        #pragma unroll
        for (int j = 0; j < 7; ++j) {
            float ev = edc[j]*(float)eb8[j];
            e[j] = ev; rs += ev;
        }
        rs += __shfl_xor(rs, 16);
        float inv = frcp(rs);
        #pragma unroll
        for (int j = 0; j < 7; ++j) w[j] += e[j]*inv;
    }
    // PV over this half's 7 slots, then cross-half combine; osT holds xsum -> +=
    float out[8];
    #pragma unroll
    for (int d = 0; d < 8; ++d) out[d] = 0.f;
    #pragma unroll
    for (int j = 0; j < 7; ++j) {
        const _Float16* vp = (j < 6) ? (sq + rws[j]*200 + 128 + hb)
                                     : (hf ? sqc + 128 + hb : sq + rws[0]*200 + 128 + hb);
        u8h vv; vv.v = *(const h8*)vp;
        float wj = w[j];
        #pragma unroll
        for (int d4 = 0; d4 < 4; ++d4) {
            h2f pr = vv.p[d4];
            out[d4*2]   += wj*(float)pr.x;
            out[d4*2+1] += wj*(float)pr.y;
        }
    }
    #pragma unroll
    for (int d = 0; d < 8; ++d) out[d] += __shfl_xor(out[d], 16);
    const int p = p0 + pix, dbase = hf*4;
    float* op = osT + (size_t)(hb + dbase)*16384 + p;
    op[0]     += out[dbase];
    op[16384] += out[dbase + 1];
    op[32768] += out[dbase + 2];
    op[49152] += out[dbase + 3];
}

// ---------------- K3: LN2 + MLP(GELU) + residual + proj ----------------
// block = 1024: pix(64) x g(16); s-broadcast f16 weights; odd-dword LDS strides.
__global__ __launch_bounds__(1024) void k_mlp(
    const float* __restrict__ osT, const float* __restrict__ n2w, const float* __restrict__ n2b,
    const float* __restrict__ b1, const float* __restrict__ b2, const float* __restrict__ pb,
    const _Float16* __restrict__ w1h, const _Float16* __restrict__ w2h, const _Float16* __restrict__ pwh,
    float* __restrict__ out)
{
    __shared__ alignas(16) _Float16 sH[64*258];   // stride 129 dwords (odd)
    __shared__ alignas(16) _Float16 sY[64*74];    // stride 37 dwords (odd)
    const int t = threadIdx.x;
    const int pix = t & 63, g = t >> 6;
    const int p = blockIdx.x*64 + pix;
    float a[64]; float s = 0.f, s2 = 0.f;
    #pragma unroll
    for (int c = 0; c < 64; ++c) { float v = osT[(size_t)c*16384 + p]; a[c] = v; s += v; s2 += v*v; }
    float m = s*0.015625f;
    float rstd = rsqrtf(fmaxf(s2*0.015625f - m*m, 0.f) + 1e-5f);
    h2f av[32];
    #pragma unroll
    for (int c = 0; c < 32; ++c) {
        float e0 = (a[2*c]   - m)*rstd*n2w[2*c]   + n2b[2*c];
        float e1 = (a[2*c+1] - m)*rstd*n2w[2*c+1] + n2b[2*c+1];
        av[c] = h2f{(_Float16)e0, (_Float16)e1};
    }
    // fc1 + exact GELU: 16 outputs per thread, ILP-4
    #pragma unroll
    for (int i4 = 0; i4 < 16; i4 += 4) {
        const int j = g*16 + i4;
        const h2f* wr = (const h2f*)(w1h + (size_t)j*64);
        float a0 = b1[j], a1 = b1[j+1], a2 = b1[j+2], a3 = b1[j+3];
        #pragma unroll
        for (int cp = 0; cp < 32; ++cp) {
            h2f xv = av[cp];
            a0 = fdot2f(xv, wr[cp],      a0);
            a1 = fdot2f(xv, wr[32 + cp], a1);
            a2 = fdot2f(xv, wr[64 + cp], a2);
            a3 = fdot2f(xv, wr[96 + cp], a3);
        }
        sH[pix*258 + j]     = (_Float16)(0.5f*a0*(1.f + erff(a0*0.70710678f)));
        sH[pix*258 + j + 1] = (_Float16)(0.5f*a1*(1.f + erff(a1*0.70710678f)));
        sH[pix*258 + j + 2] = (_Float16)(0.5f*a2*(1.f + erff(a2*0.70710678f)));
        sH[pix*258 + j + 3] = (_Float16)(0.5f*a3*(1.f + erff(a3*0.70710678f)));
    }
    __syncthreads();
    // fc2 + residual: 4 outputs per thread
    {
        const int o = g*4;
        const h2f* wr = (const h2f*)(w2h + (size_t)o*256);
        const h2f* hr = (const h2f*)(sH + pix*258);
        float a0 = b2[o], a1 = b2[o+1], a2 = b2[o+2], a3 = b2[o+3];
        #pragma unroll 32
        for (int jp = 0; jp < 128; ++jp) {
            h2f hv = hr[jp];
            a0 = fdot2f(hv, wr[jp],       a0);
            a1 = fdot2f(hv, wr[128 + jp], a1);
            a2 = fdot2f(hv, wr[256 + jp], a2);
            a3 = fdot2f(hv, wr[384 + jp], a3);
        }
        a0 += osT[(size_t)o*16384 + p];
        a1 += osT[(size_t)(o+1)*16384 + p];
        a2 += osT[(size_t)(o+2)*16384 + p];
        a3 += osT[(size_t)(o+3)*16384 + p];
        sY[pix*74 + o]     = (_Float16)a0;
        sY[pix*74 + o + 1] = (_Float16)a1;
        sY[pix*74 + o + 2] = (_Float16)a2;
        sY[pix*74 + o + 3] = (_Float16)a3;
    }
    __syncthreads();
    // proj: 4 outputs per thread
    {
        const int o = g*4;
        const h2f* wr = (const h2f*)(pwh + (size_t)o*64);
        const h2f* yr = (const h2f*)(sY + pix*74);
        float a0 = pb[o], a1 = pb[o+1], a2 = pb[o+2], a3 = pb[o+3];
        #pragma unroll
        for (int cp = 0; cp < 32; ++cp) {
            h2f yv = yr[cp];
            a0 = fdot2f(yv, wr[cp],      a0);
            a1 = fdot2f(yv, wr[32 + cp], a1);
            a2 = fdot2f(yv, wr[64 + cp], a2);
            a3 = fdot2f(yv, wr[96 + cp], a3);
        }
        const int bimg = blockIdx.x >> 6, hh = blockIdx.x & 63;
        float* ob = out + ((size_t)((bimg*64 + o)*64 + hh))*64 + pix;
        ob[0]     = a0;
        ob[4096]  = a1;
        ob[8192]  = a2;
        ob[12288] = a3;
    }
}

extern "C" void kernel_launch(void* const* d_in, const int* in_sizes, int n_in,
                              void* d_out, int out_size, void* d_ws, size_t ws_size,
                              hipStream_t stream) {
    const float* x   = (const float*)d_in[0];
    const float* n1w = (const float*)d_in[1];
    const float* n1b = (const float*)d_in[2];
    const float* qw  = (const float*)d_in[3];
    const float* qb  = (const float*)d_in[4];
    const float* rpb = (const float*)d_in[5];
    const float* n2w = (const float*)d_in[6];
    const float* n2b = (const float*)d_in[7];
    const float* w1  = (const float*)d_in[8];
    const float* b1  = (const float*)d_in[9];
    const float* w2  = (const float*)d_in[10];
    const float* b2  = (const float*)d_in[11];
    const float* pw  = (const float*)d_in[12];
    const float* pb  = (const float*)d_in[13];
    float* out = (float*)d_out;

    float* ws = (float*)d_ws;
    _Float16* qkvh   = (_Float16*)ws;              // 16384*192 f16 = 1,572,864 floats
    float*    osT    = ws + 1572864;               // 64*16384 f32  = 1,048,576 floats
    _Float16* qkvc_h = (_Float16*)(ws + 2621440);  // 192 f16 (96 floats)
    _Float16* eb7    = (_Float16*)(ws + 2621536);  // 3200 f16 (1600 floats)
    _Float16* w1h    = (_Float16*)(ws + 2623136);  // 16384 f16 (8192)
    _Float16* w2h    = (_Float16*)(ws + 2631328);  // 16384 f16 (8192)
    _Float16* pwh    = (_Float16*)(ws + 2639520);  // 4096 f16 (2048)  -> ~10.6 MB total

    hipLaunchKernelGGL(k_qkv, dim3(521), dim3(1024), 0, stream,
                       x, n1w, n1b, qw, qb, rpb, w1, w2, pw,
                       qkvh, qkvc_h, eb7, w1h, w2h, pwh, osT);
    hipLaunchKernelGGL(k_attn, dim3(1024), dim3(256), 0, stream,
                       qkvh, qkvc_h, eb7, osT);
    hipLaunchKernelGGL(k_mlp, dim3(256), dim3(1024), 0, stream,
                       osT, n2w, n2b, b1, b2, pb, w1h, w2h, pwh, out);
}

// Round 7
// 217.764 us; speedup vs baseline: 1.0992x; 1.0992x over previous
//
#include <hip/hip_runtime.h>
#include <hip/hip_bf16.h>

// CausalAttentionModule: B=4, C=64, H=W=64, NH=8, hd=8, BL=5, BS=25, MASK_ONES=12
// Round 7: fix round-6's 12x HBM write amplification (scattered 8B qkv stores) via
// LDS-staged coalesced stores; conflict-free odd-dword LDS strides (194 f16 = 97 dw);
// wave-uniform weight rows in k_mlp (s_load broadcast); 32px k_attn blocks.

typedef _Float16 h2f __attribute__((ext_vector_type(2)));
typedef _Float16 h8  __attribute__((ext_vector_type(8)));
union u8h { h8 v; h2f p[4]; };
union pk4 { _Float16 h[4]; unsigned int u[2]; };

__device__ __forceinline__ float fdot2f(h2f a, h2f b, float c) {
#if defined(__has_builtin)
#if __has_builtin(__builtin_amdgcn_fdot2)
    return __builtin_amdgcn_fdot2(a, b, c, false);
#else
    return c + (float)a.x*(float)b.x + (float)a.y*(float)b.y;
#endif
#else
    return c + (float)a.x*(float)b.x + (float)a.y*(float)b.y;
#endif
}
__device__ __forceinline__ float dot8(u8h a, u8h b) {
    float c = 0.f;
    c = fdot2f(a.p[0], b.p[0], c);
    c = fdot2f(a.p[1], b.p[1], c);
    c = fdot2f(a.p[2], b.p[2], c);
    c = fdot2f(a.p[3], b.p[3], c);
    return c;
}
__device__ __forceinline__ float frcp(float x) {
#if defined(__has_builtin)
#if __has_builtin(__builtin_amdgcn_rcpf)
    return __builtin_amdgcn_rcpf(x);
#else
    return 1.0f/x;
#endif
#else
    return 1.0f/x;
#endif
}
// unaligned-safe LDS ops (odd-dword strides make 16B types 4B-aligned)
__device__ __forceinline__ u8h ldh8(const _Float16* p) { u8h r; __builtin_memcpy(&r, p, 16); return r; }
__device__ __forceinline__ void st16(_Float16* d, const float4& v) { __builtin_memcpy(d, &v, 16); }
__device__ __forceinline__ float4 ld16(const _Float16* p) { float4 v; __builtin_memcpy(&v, p, 16); return v; }

#define SC 0.35355339059327373f  // 1/sqrt(8)

// ---------------- K1: LN1+QKV (256) | xsum (256) | wconv (8) | setup (1) ----------------
__global__ __launch_bounds__(1024) void k_qkv(
    const float* __restrict__ x, const float* __restrict__ n1w, const float* __restrict__ n1b,
    const float* __restrict__ qw, const float* __restrict__ qb, const float* __restrict__ rpb,
    const float* __restrict__ w1, const float* __restrict__ w2, const float* __restrict__ pw,
    _Float16* __restrict__ qkvh, _Float16* __restrict__ qkvc_h, _Float16* __restrict__ eb7,
    _Float16* __restrict__ w1h, _Float16* __restrict__ w2h, _Float16* __restrict__ pwh,
    float* __restrict__ osT)
{
    __shared__ float smem[6208];   // union: xsum pad plane (4624 f32) | sOut (64x194 f16)
    const int t = threadIdx.x, bid = blockIdx.x;
    if (bid < 256) {
        _Float16* sOut = (_Float16*)smem;      // stride 194 f16 (97 dwords, odd -> conflict-free)
        const int pix = t & 63, g = t >> 6;
        const int p = bid*64 + pix;
        const int b = p >> 12, hw = p & 4095;
        const float* xp = x + (size_t)b*262144 + hw;
        float xr[64]; float s = 0.f, s2 = 0.f;
        #pragma unroll
        for (int c = 0; c < 64; ++c) { float v = xp[(size_t)c*4096]; xr[c] = v; s += v; s2 += v*v; }
        float m = s*0.015625f;
        float rstd = rsqrtf(fmaxf(s2*0.015625f - m*m, 0.f) + 1e-5f);
        #pragma unroll
        for (int c = 0; c < 64; ++c) xr[c] = (xr[c] - m)*rstd*n1w[c] + n1b[c];
        #pragma unroll
        for (int i4 = 0; i4 < 12; i4 += 4) {
            const int o = g*12 + i4;           // wave-uniform -> s_load weights
            const float* wr = qw + o*64;
            float a0 = qb[o], a1 = qb[o+1], a2 = qb[o+2], a3 = qb[o+3];
            #pragma unroll 16
            for (int c = 0; c < 64; ++c) {
                float xv = xr[c];
                a0 += xv*wr[c]; a1 += xv*wr[64+c]; a2 += xv*wr[128+c]; a3 += xv*wr[192+c];
            }
            pk4 pk;
            pk.h[0]=(_Float16)a0; pk.h[1]=(_Float16)a1; pk.h[2]=(_Float16)a2; pk.h[3]=(_Float16)a3;
            __builtin_memcpy(sOut + pix*194 + o, &pk, 8);
        }
        __syncthreads();
        // coalesced f16 store: 64 rows x 24 float4, contiguous
        for (int i = t; i < 1536; i += 1024) {
            int pp = i/24, d4 = i%24;
            ((float4*)qkvh)[(size_t)bid*1536 + i] = ld16(sOut + pp*194 + d4*8);
        }
        return;
    }
    if (bid < 512) {
        float* sxp = smem;
        const int plane = bid - 256;                 // b*64 + c
        for (int i = t; i < 4624; i += 1024) sxp[i] = 0.f;
        __syncthreads();
        const float* xp = x + (size_t)plane*4096;
        for (int i = t; i < 4096; i += 1024) {
            int r = i >> 6, w = i & 63;
            sxp[(r + 2)*68 + (w + 2)] = xp[i];
        }
        __syncthreads();
        const int c = plane & 63, b = plane >> 6;
        float* op = osT + (size_t)c*16384 + b*4096;
        for (int i = t; i < 4096; i += 1024) {
            int r = i >> 6, w = i & 63;
            const float* s0 = sxp + r*68 + w;
            float sv = s0[0]+s0[1]+s0[2]+s0[3]+s0[4]
                     + s0[68]+s0[69]+s0[70]+s0[71]+s0[72]
                     + s0[136]+s0[137];
            op[i] = sv;
        }
        return;
    }
    if (bid < 520) {
        const int cid = bid - 512;
        for (int i = t; i < 4608; i += 1024) {
            int j = cid*4608 + i;
            if (j < 16384)      w1h[j]          = (_Float16)w1[j];
            else if (j < 32768) w2h[j - 16384]  = (_Float16)w2[j - 16384];
            else                pwh[j - 32768]  = (_Float16)pw[j - 32768];
        }
        return;
    }
    // setup: qkv_const = n1b @ qkv_w^T + qkv_b; 7-slot exp(bias) table
    if (t < 192) {
        float acc = qb[t];
        for (int c = 0; c < 64; ++c) acc += n1b[c]*qw[t*64 + c];
        qkvc_h[t] = (_Float16)acc;
    }
    for (int i = t; i < 3200; i += 1024) {
        int j = i & 7, hf = (i >> 3) & 1, r = i >> 4;   // r = h*25+q
        int h = r/25, q = r - h*25;
        float v = 0.f;
        if (j < 6) {
            int k = hf*6 + j;
            int ridx = (q/5 - k/5 + 4)*9 + (q%5 - k%5 + 4);
            v = __expf(rpb[ridx*8 + h]);
        } else if (j == 6 && hf) {
            for (int k = 12; k < 25; ++k) {
                int ridx = (q/5 - k/5 + 4)*9 + (q%5 - k%5 + 4);
                v += __expf(rpb[ridx*8 + h]);
            }
        }
        eb7[i] = (_Float16)v;
    }
}

// ---------------- K2: attention, k-split halves via shfl_xor(32) ----------------
// block = 512: pix(32) | hf(1) | head(8); 512 blocks of 32 pixels.
// half0 = k {0..5} + dummy(bias 0); half1 = k {6..11} + const-tail slot.
__global__ __launch_bounds__(512) void k_attn(
    const _Float16* __restrict__ qkvh, const _Float16* __restrict__ qkvc_h,
    const _Float16* __restrict__ eb7g, float* __restrict__ osT)
{
    __shared__ _Float16 sq[108*194];              // stride 194 f16 -> conflict-free col reads
    __shared__ alignas(16) _Float16 seb[3200];    // [h][q][hf][8]
    __shared__ alignas(16) _Float16 sqc[192];
    const int t = threadIdx.x;
    const int p0 = blockIdx.x*32;
    const int b = p0 >> 12, hw0 = p0 & 4095, hrow = hw0 >> 6, w0c = hw0 & 63;

    for (int i = t; i < 1600; i += 512) ((unsigned int*)seb)[i] = ((const unsigned int*)eb7g)[i];
    if (t < 96) ((unsigned int*)sqc)[t] = ((const unsigned int*)qkvc_h)[t];
    // stage qkv window: rows (hrow-2..hrow) x cols (w0c-2..w0c+33), OOB -> const row
    for (int i = t; i < 2592; i += 512) {
        int row = i/24, d4 = i%24;
        int rr = row/36, cc = row%36;
        int gr = hrow - 2 + rr, gc = w0c - 2 + cc;
        float4 v = (gr >= 0 && gc >= 0 && gc < 64)
            ? ((const float4*)qkvh)[(size_t)((b << 12) + (gr << 6) + gc)*24 + d4]
            : ((const float4*)qkvc_h)[d4];
        st16(sq + row*194 + d4*8, v);
    }
    __syncthreads();

    const int pix = t & 31, hf = (t >> 5) & 1, h = t >> 6, hb = h*8;
    int rws[6];
    #pragma unroll
    for (int j = 0; j < 6; ++j) { int k = hf*6 + j; rws[j] = (k/5)*36 + pix + (k%5); }
    u8h kreg[7];
    #pragma unroll
    for (int j = 0; j < 6; ++j) kreg[j] = ldh8(sq + rws[j]*194 + 64 + hb);
    kreg[6] = hf ? ldh8(sqc + 64 + hb) : kreg[0];
    u8h qcu = ldh8(sqc + hb);
    float edc[7];
    #pragma unroll
    for (int j = 0; j < 7; ++j) edc[j] = __expf(dot8(qcu, kreg[j])*SC);
    float w[7];
    #pragma unroll
    for (int j = 0; j < 7; ++j) w[j] = 0.f;
    const _Float16* ebbase = seb + h*400 + hf*8;

    // 12 real q rows
    for (int sIdx = 0; sIdx < 12; ++sIdx) {
        int rq = (sIdx/5)*36 + pix + (sIdx%5);
        u8h qu = ldh8(sq + rq*194 + hb);
        h8 eb8; __builtin_memcpy(&eb8, ebbase + sIdx*16, 16);
        float e[7]; float rs = 0.f;
        #pragma unroll
        for (int j = 0; j < 7; ++j) {
            float ev = __expf(dot8(qu, kreg[j])*SC)*(float)eb8[j];
            e[j] = ev; rs += ev;
        }
        rs += __shfl_xor(rs, 32);
        float inv = frcp(rs);
        #pragma unroll
        for (int j = 0; j < 7; ++j) w[j] += e[j]*inv;
    }
    // 13 constant q rows: dots shared (edc), bias row differs
    for (int q = 12; q < 25; ++q) {
        h8 eb8; __builtin_memcpy(&eb8, ebbase + q*16, 16);
        float e[7]; float rs = 0.f;
        #pragma unroll
        for (int j = 0; j < 7; ++j) {
            float ev = edc[j]*(float)eb8[j];
            e[j] = ev; rs += ev;
        }
        rs += __shfl_xor(rs, 32);
        float inv = frcp(rs);
        #pragma unroll
        for (int j = 0; j < 7; ++j) w[j] += e[j]*inv;
    }
    // PV over this half's 7 slots; cross-half combine; osT holds xsum -> +=
    float out[8];
    #pragma unroll
    for (int d = 0; d < 8; ++d) out[d] = 0.f;
    #pragma unroll
    for (int j = 0; j < 7; ++j) {
        const _Float16* vp = (j < 6) ? (sq + rws[j]*194 + 128 + hb)
                                     : (hf ? sqc + 128 + hb : sq + rws[0]*194 + 128 + hb);
        u8h vv = ldh8(vp);
        float wj = w[j];
        #pragma unroll
        for (int d4 = 0; d4 < 4; ++d4) {
            h2f pr = vv.p[d4];
            out[d4*2]   += wj*(float)pr.x;
            out[d4*2+1] += wj*(float)pr.y;
        }
    }
    #pragma unroll
    for (int d = 0; d < 8; ++d) out[d] += __shfl_xor(out[d], 32);
    const int p = p0 + pix, dbase = hf*4;
    float* op = osT + (size_t)(hb + dbase)*16384 + p;
    op[0]     += out[dbase];
    op[16384] += out[dbase + 1];
    op[32768] += out[dbase + 2];
    op[49152] += out[dbase + 3];
}

// ---------------- K3: LN2 + MLP(GELU) + residual + proj ----------------
// block = 512: pix(64) x wave g(8); wave-uniform weight rows -> s_load broadcast.
__global__ __launch_bounds__(512) void k_mlp(
    const float* __restrict__ osT, const float* __restrict__ n2w, const float* __restrict__ n2b,
    const float* __restrict__ b1, const float* __restrict__ b2, const float* __restrict__ pb,
    const _Float16* __restrict__ w1h, const _Float16* __restrict__ w2h, const _Float16* __restrict__ pwh,
    float* __restrict__ out)
{
    __shared__ float sRed[2][576];                // [px*9 + g], stride 9 (odd)
    __shared__ h2f  sAv[64*33];                   // stride 33 dwords (odd)
    __shared__ alignas(16) _Float16 sH[64*258];   // stride 129 dwords (odd)
    __shared__ alignas(16) _Float16 sY[64*74];    // stride 37 dwords (odd)
    const int t = threadIdx.x;
    const int pix = t & 63, g = t >> 6;           // g wave-uniform
    const int p = blockIdx.x*64 + pix;
    const int c0 = g*8;
    // LN partials: each wave owns 8 channels
    float v[8]; float ps = 0.f, ps2 = 0.f;
    #pragma unroll
    for (int j = 0; j < 8; ++j) {
        float vv = osT[(size_t)(c0 + j)*16384 + p];
        v[j] = vv; ps += vv; ps2 += vv*vv;
    }
    sRed[0][pix*9 + g] = ps;
    sRed[1][pix*9 + g] = ps2;
    __syncthreads();
    float s = 0.f, s2 = 0.f;
    #pragma unroll
    for (int gg = 0; gg < 8; ++gg) { s += sRed[0][pix*9 + gg]; s2 += sRed[1][pix*9 + gg]; }
    float m = s*0.015625f;
    float rstd = rsqrtf(fmaxf(s2*0.015625f - m*m, 0.f) + 1e-5f);
    #pragma unroll
    for (int k = 0; k < 4; ++k) {
        float e0 = (v[2*k]   - m)*rstd*n2w[c0 + 2*k]   + n2b[c0 + 2*k];
        float e1 = (v[2*k+1] - m)*rstd*n2w[c0 + 2*k+1] + n2b[c0 + 2*k+1];
        sAv[pix*33 + g*4 + k] = h2f{(_Float16)e0, (_Float16)e1};
    }
    __syncthreads();
    // fc1 + exact GELU: 32 outputs per thread (wave-uniform rows), ILP-4
    const h2f* avr = sAv + pix*33;
    #pragma unroll
    for (int i4 = 0; i4 < 32; i4 += 4) {
        const int j = g*32 + i4;
        const h2f* wr = (const h2f*)(w1h + (size_t)j*64);
        float a0 = b1[j], a1 = b1[j+1], a2 = b1[j+2], a3 = b1[j+3];
        #pragma unroll
        for (int cp = 0; cp < 32; ++cp) {
            h2f xv = avr[cp];
            a0 = fdot2f(xv, wr[cp],      a0);
            a1 = fdot2f(xv, wr[32 + cp], a1);
            a2 = fdot2f(xv, wr[64 + cp], a2);
            a3 = fdot2f(xv, wr[96 + cp], a3);
        }
        sH[pix*258 + j]     = (_Float16)(0.5f*a0*(1.f + erff(a0*0.70710678f)));
        sH[pix*258 + j + 1] = (_Float16)(0.5f*a1*(1.f + erff(a1*0.70710678f)));
        sH[pix*258 + j + 2] = (_Float16)(0.5f*a2*(1.f + erff(a2*0.70710678f)));
        sH[pix*258 + j + 3] = (_Float16)(0.5f*a3*(1.f + erff(a3*0.70710678f)));
    }
    __syncthreads();
    // fc2 + residual: 8 outputs per thread
    const h2f* hr = (const h2f*)(sH + pix*258);
    #pragma unroll
    for (int m4 = 0; m4 < 8; m4 += 4) {
        const int o = g*8 + m4;
        const h2f* wr = (const h2f*)(w2h + (size_t)o*256);
        float a0 = b2[o], a1 = b2[o+1], a2 = b2[o+2], a3 = b2[o+3];
        #pragma unroll 32
        for (int jp = 0; jp < 128; ++jp) {
            h2f hv = hr[jp];
            a0 = fdot2f(hv, wr[jp],       a0);
            a1 = fdot2f(hv, wr[128 + jp], a1);
            a2 = fdot2f(hv, wr[256 + jp], a2);
            a3 = fdot2f(hv, wr[384 + jp], a3);
        }
        a0 += osT[(size_t)o*16384 + p];
        a1 += osT[(size_t)(o+1)*16384 + p];
        a2 += osT[(size_t)(o+2)*16384 + p];
        a3 += osT[(size_t)(o+3)*16384 + p];
        sY[pix*74 + o]     = (_Float16)a0;
        sY[pix*74 + o + 1] = (_Float16)a1;
        sY[pix*74 + o + 2] = (_Float16)a2;
        sY[pix*74 + o + 3] = (_Float16)a3;
    }
    __syncthreads();
    // proj: 8 outputs per thread
    const h2f* yr = (const h2f*)(sY + pix*74);
    const int bimg = p >> 12, hw = p & 4095, hh = hw >> 6;
    #pragma unroll
    for (int m4 = 0; m4 < 8; m4 += 4) {
        const int o = g*8 + m4;
        const h2f* wr = (const h2f*)(pwh + (size_t)o*64);
        float a0 = pb[o], a1 = pb[o+1], a2 = pb[o+2], a3 = pb[o+3];
        #pragma unroll
        for (int cp = 0; cp < 32; ++cp) {
            h2f yv = yr[cp];
            a0 = fdot2f(yv, wr[cp],      a0);
            a1 = fdot2f(yv, wr[32 + cp], a1);
            a2 = fdot2f(yv, wr[64 + cp], a2);
            a3 = fdot2f(yv, wr[96 + cp], a3);
        }
        float* ob = out + ((size_t)((bimg*64 + o)*64 + hh))*64 + pix;
        ob[0]     = a0;
        ob[4096]  = a1;
        ob[8192]  = a2;
        ob[12288] = a3;
    }
}

extern "C" void kernel_launch(void* const* d_in, const int* in_sizes, int n_in,
                              void* d_out, int out_size, void* d_ws, size_t ws_size,
                              hipStream_t stream) {
    const float* x   = (const float*)d_in[0];
    const float* n1w = (const float*)d_in[1];
    const float* n1b = (const float*)d_in[2];
    const float* qw  = (const float*)d_in[3];
    const float* qb  = (const float*)d_in[4];
    const float* rpb = (const float*)d_in[5];
    const float* n2w = (const float*)d_in[6];
    const float* n2b = (const float*)d_in[7];
    const float* w1  = (const float*)d_in[8];
    const float* b1  = (const float*)d_in[9];
    const float* w2  = (const float*)d_in[10];
    const float* b2  = (const float*)d_in[11];
    const float* pw  = (const float*)d_in[12];
    const float* pb  = (const float*)d_in[13];
    float* out = (float*)d_out;

    float* ws = (float*)d_ws;
    _Float16* qkvh   = (_Float16*)ws;              // 16384*192 f16 = 1,572,864 floats
    float*    osT    = ws + 1572864;               // 64*16384 f32  = 1,048,576 floats
    _Float16* qkvc_h = (_Float16*)(ws + 2621440);  // 192 f16
    _Float16* eb7    = (_Float16*)(ws + 2621536);  // 3200 f16
    _Float16* w1h    = (_Float16*)(ws + 2623136);  // 16384 f16
    _Float16* w2h    = (_Float16*)(ws + 2631328);  // 16384 f16
    _Float16* pwh    = (_Float16*)(ws + 2639520);  // 4096 f16  -> ~10.6 MB total

    hipLaunchKernelGGL(k_qkv, dim3(521), dim3(1024), 0, stream,
                       x, n1w, n1b, qw, qb, rpb, w1, w2, pw,
                       qkvh, qkvc_h, eb7, w1h, w2h, pwh, osT);
    hipLaunchKernelGGL(k_attn, dim3(512), dim3(512), 0, stream,
                       qkvh, qkvc_h, eb7, osT);
    hipLaunchKernelGGL(k_mlp, dim3(256), dim3(512), 0, stream,
                       osT, n2w, n2b, b1, b2, pb, w1h, w2h, pwh, out);
}

// Round 8
// 214.972 us; speedup vs baseline: 1.1135x; 1.0130x over previous
//
#include <hip/hip_runtime.h>
#include <hip/hip_bf16.h>

// CausalAttentionModule: B=4, C=64, H=W=64, NH=8, hd=8, BL=5, BS=25, MASK_ONES=12
// Round 8: two kernels. K1 = LN1+QKV (LDS-staged x) | xsum | wconv | setup.
// K2 = fused attention + LN2 + MLP + proj (out_sumed stays in LDS; phase-overlaid
// LDS regions; 2 blocks/CU). Rationale: every kernel window pays a large ambient
// cost (poison/restore drain) -> fewer windows + less real traffic.

typedef _Float16 h2f __attribute__((ext_vector_type(2)));
typedef _Float16 h8  __attribute__((ext_vector_type(8)));
union u8h { h8 v; h2f p[4]; };
union pk4 { _Float16 h[4]; unsigned int u[2]; };

__device__ __forceinline__ float fdot2f(h2f a, h2f b, float c) {
#if defined(__has_builtin)
#if __has_builtin(__builtin_amdgcn_fdot2)
    return __builtin_amdgcn_fdot2(a, b, c, false);
#else
    return c + (float)a.x*(float)b.x + (float)a.y*(float)b.y;
#endif
#else
    return c + (float)a.x*(float)b.x + (float)a.y*(float)b.y;
#endif
}
__device__ __forceinline__ float dot8(u8h a, u8h b) {
    float c = 0.f;
    c = fdot2f(a.p[0], b.p[0], c);
    c = fdot2f(a.p[1], b.p[1], c);
    c = fdot2f(a.p[2], b.p[2], c);
    c = fdot2f(a.p[3], b.p[3], c);
    return c;
}
__device__ __forceinline__ float frcp(float x) {
#if defined(__has_builtin)
#if __has_builtin(__builtin_amdgcn_rcpf)
    return __builtin_amdgcn_rcpf(x);
#else
    return 1.0f/x;
#endif
#else
    return 1.0f/x;
#endif
}
__device__ __forceinline__ u8h ldh8(const _Float16* p) { u8h r; __builtin_memcpy(&r, p, 16); return r; }
__device__ __forceinline__ void st16(_Float16* d, const float4& v) { __builtin_memcpy(d, &v, 16); }
__device__ __forceinline__ float4 ld16(const _Float16* p) { float4 v; __builtin_memcpy(&v, p, 16); return v; }

#define SC 0.35355339059327373f  // 1/sqrt(8)

// ---------------- K1: LN1+QKV (256) | xsum (256) | wconv (8) | setup (1) ----------------
__global__ __launch_bounds__(1024) void k_qkv(
    const float* __restrict__ x, const float* __restrict__ n1w, const float* __restrict__ n1b,
    const float* __restrict__ qw, const float* __restrict__ qb, const float* __restrict__ rpb,
    const float* __restrict__ w1, const float* __restrict__ w2, const float* __restrict__ pw,
    _Float16* __restrict__ qkvh, _Float16* __restrict__ qkvc_h, _Float16* __restrict__ eb7,
    _Float16* __restrict__ w1h, _Float16* __restrict__ w2h, _Float16* __restrict__ pwh,
    float* __restrict__ osT)
{
    __shared__ float smem[10368];   // main: sXf 4160 f32 + sOut 6208 dw | xsum: 4624 f32
    const int t = threadIdx.x, bid = blockIdx.x;
    if (bid < 256) {
        float* sXf = smem;                             // 64 x 65 f32 (stride 65, odd)
        _Float16* sOut = (_Float16*)(smem + 4160);     // 64 x 194 f16 (97 dw, odd)
        const int p0 = bid*64;
        const int b = p0 >> 12, hw0 = p0 & 4095;
        // stage x tile once (kills 16x redundant global reads)
        for (int i = t; i < 4096; i += 1024) {
            int c = i >> 6, pp = i & 63;
            sXf[pp*65 + c] = x[(size_t)b*262144 + (size_t)c*4096 + hw0 + pp];
        }
        __syncthreads();
        const int pix = t & 63, g = t >> 6;
        float xr[64]; float s = 0.f, s2 = 0.f;
        #pragma unroll
        for (int c = 0; c < 64; ++c) { float v = sXf[pix*65 + c]; xr[c] = v; s += v; s2 += v*v; }
        float m = s*0.015625f;
        float rstd = rsqrtf(fmaxf(s2*0.015625f - m*m, 0.f) + 1e-5f);
        #pragma unroll
        for (int c = 0; c < 64; ++c) xr[c] = (xr[c] - m)*rstd*n1w[c] + n1b[c];
        #pragma unroll
        for (int i4 = 0; i4 < 12; i4 += 4) {
            const int o = g*12 + i4;                   // wave-uniform -> s_load weights
            const float* wr = qw + o*64;
            float a0 = qb[o], a1 = qb[o+1], a2 = qb[o+2], a3 = qb[o+3];
            #pragma unroll 16
            for (int c = 0; c < 64; ++c) {
                float xv = xr[c];
                a0 += xv*wr[c]; a1 += xv*wr[64+c]; a2 += xv*wr[128+c]; a3 += xv*wr[192+c];
            }
            pk4 pk;
            pk.h[0]=(_Float16)a0; pk.h[1]=(_Float16)a1; pk.h[2]=(_Float16)a2; pk.h[3]=(_Float16)a3;
            __builtin_memcpy(sOut + pix*194 + o, &pk, 8);
        }
        __syncthreads();
        for (int i = t; i < 1536; i += 1024) {
            int pp = i/24, d4 = i%24;
            ((float4*)qkvh)[(size_t)bid*1536 + i] = ld16(sOut + pp*194 + d4*8);
        }
        return;
    }
    if (bid < 512) {
        float* sxp = smem;
        const int plane = bid - 256;                 // b*64 + c
        for (int i = t; i < 4624; i += 1024) sxp[i] = 0.f;
        __syncthreads();
        const float* xp = x + (size_t)plane*4096;
        for (int i = t; i < 4096; i += 1024) {
            int r = i >> 6, w = i & 63;
            sxp[(r + 2)*68 + (w + 2)] = xp[i];
        }
        __syncthreads();
        const int c = plane & 63, b = plane >> 6;
        float* op = osT + (size_t)c*16384 + b*4096;
        for (int i = t; i < 4096; i += 1024) {
            int r = i >> 6, w = i & 63;
            const float* s0 = sxp + r*68 + w;
            float sv = s0[0]+s0[1]+s0[2]+s0[3]+s0[4]
                     + s0[68]+s0[69]+s0[70]+s0[71]+s0[72]
                     + s0[136]+s0[137];
            op[i] = sv;
        }
        return;
    }
    if (bid < 520) {
        const int cid = bid - 512;
        for (int i = t; i < 4608; i += 1024) {
            int j = cid*4608 + i;
            if (j < 16384)      w1h[j]          = (_Float16)w1[j];
            else if (j < 32768) w2h[j - 16384]  = (_Float16)w2[j - 16384];
            else                pwh[j - 32768]  = (_Float16)pw[j - 32768];
        }
        return;
    }
    // setup: qkv_const = n1b @ qkv_w^T + qkv_b; 7-slot exp(bias) table
    if (t < 192) {
        float acc = qb[t];
        for (int c = 0; c < 64; ++c) acc += n1b[c]*qw[t*64 + c];
        qkvc_h[t] = (_Float16)acc;
    }
    for (int i = t; i < 3200; i += 1024) {
        int j = i & 7, hf = (i >> 3) & 1, r = i >> 4;   // r = h*25+q
        int h = r/25, q = r - h*25;
        float v = 0.f;
        if (j < 6) {
            int k = hf*6 + j;
            int ridx = (q/5 - k/5 + 4)*9 + (q%5 - k%5 + 4);
            v = __expf(rpb[ridx*8 + h]);
        } else if (j == 6 && hf) {
            for (int k = 12; k < 25; ++k) {
                int ridx = (q/5 - k/5 + 4)*9 + (q%5 - k%5 + 4);
                v += __expf(rpb[ridx*8 + h]);
            }
        }
        eb7[i] = (_Float16)v;
    }
}

// ---------------- K2: fused attention + LN2 + MLP + proj ----------------
// block = 512 thr, 32 pixels. Attention: pix(32)|hf(1)|head(8), k-split + shfl_xor(32).
// Then out_sumed stays in LDS: LN2 -> fc1(GELU) -> fc2+resid -> proj -> out.
// LDS phase overlay: post-attention arrays live inside the dead 42 KB qkv window.
__global__ __launch_bounds__(512) void k_fused(
    const _Float16* __restrict__ qkvh, const _Float16* __restrict__ qkvc_h,
    const _Float16* __restrict__ eb7g, const float* __restrict__ osT,
    const float* __restrict__ n2w, const float* __restrict__ n2b,
    const float* __restrict__ b1, const float* __restrict__ b2, const float* __restrict__ pb,
    const _Float16* __restrict__ w1h, const _Float16* __restrict__ w2h, const _Float16* __restrict__ pwh,
    float* __restrict__ out)
{
    __shared__ alignas(16) char smem[57040];
    _Float16* sq   = (_Float16*)(smem);            // 108 x 194 f16 = 41904 B (attn phase)
    _Float16* seb  = (_Float16*)(smem + 41920);    // 3200 f16 = 6400 B     (attn phase)
    _Float16* sqc  = (_Float16*)(smem + 48320);    // 192 f16               (attn phase)
    float*    sOs  = (float*)   (smem + 48704);    // 32 x 65 f32 = 8320 B  (whole kernel)
    // overlays inside dead sq after attention:
    _Float16* sH   = (_Float16*)(smem);            // 32 x 258 f16 = 16512 B
    h2f*      sAv  = (h2f*)     (smem + 16512);    // 32 x 34 h2f = 4352 B
    float*    sRW  = (float*)   (smem + 20880);    // 8 x 33 px float2 = 2112 B
    float*    sMR  = (float*)   (smem + 23008);    // 32 float2 = 256 B
    _Float16* sY   = (_Float16*)(smem + 41920);    // 32 x 74 f16 (over seb)

    const int t = threadIdx.x;
    const int p0 = blockIdx.x*32;
    const int b = p0 >> 12, hw0 = p0 & 4095, hrow = hw0 >> 6, w0c = hw0 & 63;

    // ---- phase 0: stage ----
    for (int i = t; i < 1600; i += 512) ((unsigned int*)seb)[i] = ((const unsigned int*)eb7g)[i];
    if (t < 96) ((unsigned int*)sqc)[t] = ((const unsigned int*)qkvc_h)[t];
    for (int i = t; i < 2592; i += 512) {
        int row = i/24, d4 = i%24;
        int rr = row/36, cc = row%36;
        int gr = hrow - 2 + rr, gc = w0c - 2 + cc;
        float4 v = (gr >= 0 && gc >= 0 && gc < 64)
            ? ((const float4*)qkvh)[(size_t)((b << 12) + (gr << 6) + gc)*24 + d4]
            : ((const float4*)qkvc_h)[d4];
        st16(sq + row*194 + d4*8, v);
    }
    for (int i = t; i < 2048; i += 512) {           // xsum -> sOs
        int c = i >> 5, pp = i & 31;
        sOs[pp*65 + c] = osT[(size_t)c*16384 + p0 + pp];
    }
    __syncthreads();

    // ---- phase 1: attention ----
    {
        const int pix = t & 31, hf = (t >> 5) & 1, h = t >> 6, hb = h*8;
        int rws[6];
        #pragma unroll
        for (int j = 0; j < 6; ++j) { int k = hf*6 + j; rws[j] = (k/5)*36 + pix + (k%5); }
        u8h kreg[7];
        #pragma unroll
        for (int j = 0; j < 6; ++j) kreg[j] = ldh8(sq + rws[j]*194 + 64 + hb);
        kreg[6] = hf ? ldh8(sqc + 64 + hb) : kreg[0];
        u8h qcu = ldh8(sqc + hb);
        float edc[7];
        #pragma unroll
        for (int j = 0; j < 7; ++j) edc[j] = __expf(dot8(qcu, kreg[j])*SC);
        float w[7];
        #pragma unroll
        for (int j = 0; j < 7; ++j) w[j] = 0.f;
        const _Float16* ebbase = seb + h*400 + hf*8;

        for (int sIdx = 0; sIdx < 12; ++sIdx) {
            int rq = (sIdx/5)*36 + pix + (sIdx%5);
            u8h qu = ldh8(sq + rq*194 + hb);
            h8 eb8; __builtin_memcpy(&eb8, ebbase + sIdx*16, 16);
            float e[7]; float rs = 0.f;
            #pragma unroll
            for (int j = 0; j < 7; ++j) {
                float ev = __expf(dot8(qu, kreg[j])*SC)*(float)eb8[j];
                e[j] = ev; rs += ev;
            }
            rs += __shfl_xor(rs, 32);
            float inv = frcp(rs);
            #pragma unroll
            for (int j = 0; j < 7; ++j) w[j] += e[j]*inv;
        }
        for (int q = 12; q < 25; ++q) {
            h8 eb8; __builtin_memcpy(&eb8, ebbase + q*16, 16);
            float e[7]; float rs = 0.f;
            #pragma unroll
            for (int j = 0; j < 7; ++j) {
                float ev = edc[j]*(float)eb8[j];
                e[j] = ev; rs += ev;
            }
            rs += __shfl_xor(rs, 32);
            float inv = frcp(rs);
            #pragma unroll
            for (int j = 0; j < 7; ++j) w[j] += e[j]*inv;
        }
        float o8[8];
        #pragma unroll
        for (int d = 0; d < 8; ++d) o8[d] = 0.f;
        #pragma unroll
        for (int j = 0; j < 7; ++j) {
            const _Float16* vp = (j < 6) ? (sq + rws[j]*194 + 128 + hb)
                                         : (hf ? sqc + 128 + hb : sq + rws[0]*194 + 128 + hb);
            u8h vv = ldh8(vp);
            float wj = w[j];
            #pragma unroll
            for (int d4 = 0; d4 < 4; ++d4) {
                h2f pr = vv.p[d4];
                o8[d4*2]   += wj*(float)pr.x;
                o8[d4*2+1] += wj*(float)pr.y;
            }
        }
        #pragma unroll
        for (int d = 0; d < 8; ++d) o8[d] += __shfl_xor(o8[d], 32);
        const int c0 = hb + hf*4;
        float* ap = sOs + pix*65 + c0;
        #pragma unroll
        for (int j = 0; j < 4; ++j) ap[j] += o8[hf*4 + j];
    }
    __syncthreads();   // sq/seb/sqc dead; sOs = out_sumed

    // ---- phase 2: LN2 reduce ----
    const int pix = t & 31, sl = t >> 5;             // sl in [0,16)
    const int c4 = sl*4;
    float ps = 0.f, ps2 = 0.f;
    float vch[4];
    #pragma unroll
    for (int j = 0; j < 4; ++j) {
        float v = sOs[pix*65 + c4 + j];
        vch[j] = v; ps += v; ps2 += v*v;
    }
    ps  += __shfl_xor(ps, 32);
    ps2 += __shfl_xor(ps2, 32);
    const int wv = t >> 6;                           // wave id = channel-group
    if (((t >> 5) & 1) == 0) {
        sRW[(wv*33 + pix)*2]     = ps;
        sRW[(wv*33 + pix)*2 + 1] = ps2;
    }
    __syncthreads();
    if (t < 32) {
        float s = 0.f, s2 = 0.f;
        #pragma unroll
        for (int g = 0; g < 8; ++g) { s += sRW[(g*33 + t)*2]; s2 += sRW[(g*33 + t)*2 + 1]; }
        float m = s*0.015625f;
        sMR[t*2]     = m;
        sMR[t*2 + 1] = rsqrtf(fmaxf(s2*0.015625f - m*m, 0.f) + 1e-5f);
    }
    __syncthreads();
    // LN apply -> sAv (f16 pairs)
    {
        float m = sMR[pix*2], r = sMR[pix*2 + 1];
        #pragma unroll
        for (int j = 0; j < 2; ++j) {
            float e0 = (vch[2*j]   - m)*r*n2w[c4 + 2*j]   + n2b[c4 + 2*j];
            float e1 = (vch[2*j+1] - m)*r*n2w[c4 + 2*j+1] + n2b[c4 + 2*j+1];
            sAv[pix*34 + sl*2 + j] = h2f{(_Float16)e0, (_Float16)e1};
        }
    }
    __syncthreads();

    // ---- phase 3: fc1 + GELU -> sH ----
    {
        const h2f* avr = sAv + pix*34;
        #pragma unroll
        for (int i4 = 0; i4 < 16; i4 += 4) {
            const int j = sl*16 + i4;
            const h2f* wr = (const h2f*)(w1h + (size_t)j*64);
            float a0 = b1[j], a1 = b1[j+1], a2 = b1[j+2], a3 = b1[j+3];
            #pragma unroll
            for (int cp = 0; cp < 32; ++cp) {
                h2f xv = avr[cp];
                a0 = fdot2f(xv, wr[cp],      a0);
                a1 = fdot2f(xv, wr[32 + cp], a1);
                a2 = fdot2f(xv, wr[64 + cp], a2);
                a3 = fdot2f(xv, wr[96 + cp], a3);
            }
            sH[pix*258 + j]     = (_Float16)(0.5f*a0*(1.f + erff(a0*0.70710678f)));
            sH[pix*258 + j + 1] = (_Float16)(0.5f*a1*(1.f + erff(a1*0.70710678f)));
            sH[pix*258 + j + 2] = (_Float16)(0.5f*a2*(1.f + erff(a2*0.70710678f)));
            sH[pix*258 + j + 3] = (_Float16)(0.5f*a3*(1.f + erff(a3*0.70710678f)));
        }
    }
    __syncthreads();

    // ---- phase 4: fc2 + residual -> sY ----
    {
        const int o = sl*4;
        const h2f* wr = (const h2f*)(w2h + (size_t)o*256);
        const h2f* hr = (const h2f*)(sH + pix*258);
        float a0 = b2[o], a1 = b2[o+1], a2 = b2[o+2], a3 = b2[o+3];
        #pragma unroll 32
        for (int jp = 0; jp < 128; ++jp) {
            h2f hv = hr[jp];
            a0 = fdot2f(hv, wr[jp],       a0);
            a1 = fdot2f(hv, wr[128 + jp], a1);
            a2 = fdot2f(hv, wr[256 + jp], a2);
            a3 = fdot2f(hv, wr[384 + jp], a3);
        }
        a0 += sOs[pix*65 + o];
        a1 += sOs[pix*65 + o + 1];
        a2 += sOs[pix*65 + o + 2];
        a3 += sOs[pix*65 + o + 3];
        sY[pix*74 + o]     = (_Float16)a0;
        sY[pix*74 + o + 1] = (_Float16)a1;
        sY[pix*74 + o + 2] = (_Float16)a2;
        sY[pix*74 + o + 3] = (_Float16)a3;
    }
    __syncthreads();

    // ---- phase 5: proj -> out ----
    {
        const int o = sl*4;
        const h2f* wr = (const h2f*)(pwh + (size_t)o*64);
        const h2f* yr = (const h2f*)(sY + pix*74);
        float a0 = pb[o], a1 = pb[o+1], a2 = pb[o+2], a3 = pb[o+3];
        #pragma unroll
        for (int cp = 0; cp < 32; ++cp) {
            h2f yv = yr[cp];
            a0 = fdot2f(yv, wr[cp],      a0);
            a1 = fdot2f(yv, wr[32 + cp], a1);
            a2 = fdot2f(yv, wr[64 + cp], a2);
            a3 = fdot2f(yv, wr[96 + cp], a3);
        }
        const int p = p0 + pix;
        const int bimg = p >> 12, hw = p & 4095, hh = hw >> 6, ww = hw & 63;
        float* ob = out + ((size_t)((bimg*64 + o)*64 + hh))*64 + ww;
        ob[0]     = a0;
        ob[4096]  = a1;
        ob[8192]  = a2;
        ob[12288] = a3;
    }
}

extern "C" void kernel_launch(void* const* d_in, const int* in_sizes, int n_in,
                              void* d_out, int out_size, void* d_ws, size_t ws_size,
                              hipStream_t stream) {
    const float* x   = (const float*)d_in[0];
    const float* n1w = (const float*)d_in[1];
    const float* n1b = (const float*)d_in[2];
    const float* qw  = (const float*)d_in[3];
    const float* qb  = (const float*)d_in[4];
    const float* rpb = (const float*)d_in[5];
    const float* n2w = (const float*)d_in[6];
    const float* n2b = (const float*)d_in[7];
    const float* w1  = (const float*)d_in[8];
    const float* b1  = (const float*)d_in[9];
    const float* w2  = (const float*)d_in[10];
    const float* b2  = (const float*)d_in[11];
    const float* pw  = (const float*)d_in[12];
    const float* pb  = (const float*)d_in[13];
    float* out = (float*)d_out;

    float* ws = (float*)d_ws;
    _Float16* qkvh   = (_Float16*)ws;              // 16384*192 f16 = 1,572,864 floats
    float*    osT    = ws + 1572864;               // 64*16384 f32  = 1,048,576 floats
    _Float16* qkvc_h = (_Float16*)(ws + 2621440);  // 192 f16
    _Float16* eb7    = (_Float16*)(ws + 2621536);  // 3200 f16
    _Float16* w1h    = (_Float16*)(ws + 2623136);  // 16384 f16
    _Float16* w2h    = (_Float16*)(ws + 2631328);  // 16384 f16
    _Float16* pwh    = (_Float16*)(ws + 2639520);  // 4096 f16  -> ~10.6 MB total

    hipLaunchKernelGGL(k_qkv, dim3(521), dim3(1024), 0, stream,
                       x, n1w, n1b, qw, qb, rpb, w1, w2, pw,
                       qkvh, qkvc_h, eb7, w1h, w2h, pwh, osT);
    hipLaunchKernelGGL(k_fused, dim3(512), dim3(512), 0, stream,
                       qkvh, qkvc_h, eb7, osT,
                       n2w, n2b, b1, b2, pb, w1h, w2h, pwh, out);
}

// Round 9
// 212.177 us; speedup vs baseline: 1.1282x; 1.0132x over previous
//
#include <hip/hip_runtime.h>
#include <hip/hip_bf16.h>

// CausalAttentionModule: B=4, C=64, H=W=64, NH=8, hd=8, BL=5, BS=25, MASK_ONES=12
// Round 9: drop osT + xsum blocks. K1 writes combined f16 rows [192 qkv | 64 x].
// K2 stages one 108x256-f16 window, computes neighbor-xsum in LDS, then fused
// attention + LN2 + MLP + proj. TCC counters are drain-contaminated; trust dur_us.

typedef _Float16 h2f __attribute__((ext_vector_type(2)));
typedef _Float16 h8  __attribute__((ext_vector_type(8)));
union u8h { h8 v; h2f p[4]; };
union pk4 { _Float16 h[4]; unsigned int u[2]; };

__device__ __forceinline__ float fdot2f(h2f a, h2f b, float c) {
#if defined(__has_builtin)
#if __has_builtin(__builtin_amdgcn_fdot2)
    return __builtin_amdgcn_fdot2(a, b, c, false);
#else
    return c + (float)a.x*(float)b.x + (float)a.y*(float)b.y;
#endif
#else
    return c + (float)a.x*(float)b.x + (float)a.y*(float)b.y;
#endif
}
__device__ __forceinline__ float dot8(u8h a, u8h b) {
    float c = 0.f;
    c = fdot2f(a.p[0], b.p[0], c);
    c = fdot2f(a.p[1], b.p[1], c);
    c = fdot2f(a.p[2], b.p[2], c);
    c = fdot2f(a.p[3], b.p[3], c);
    return c;
}
__device__ __forceinline__ float frcp(float x) {
#if defined(__has_builtin)
#if __has_builtin(__builtin_amdgcn_rcpf)
    return __builtin_amdgcn_rcpf(x);
#else
    return 1.0f/x;
#endif
#else
    return 1.0f/x;
#endif
}
__device__ __forceinline__ u8h ldh8(const _Float16* p) { u8h r; __builtin_memcpy(&r, p, 16); return r; }
__device__ __forceinline__ h2f ldh2(const _Float16* p) { h2f r; __builtin_memcpy(&r, p, 4); return r; }
__device__ __forceinline__ void st16(_Float16* d, const float4& v) { __builtin_memcpy(d, &v, 16); }
__device__ __forceinline__ float4 ld16(const _Float16* p) { float4 v; __builtin_memcpy(&v, p, 16); return v; }

#define SC 0.35355339059327373f  // 1/sqrt(8)

// ---------------- K1: LN1+QKV+x_f16 (256) | wconv (8) | setup (1) ----------------
__global__ __launch_bounds__(1024) void k_qkv(
    const float* __restrict__ x, const float* __restrict__ n1w, const float* __restrict__ n1b,
    const float* __restrict__ qw, const float* __restrict__ qb, const float* __restrict__ rpb,
    const float* __restrict__ w1, const float* __restrict__ w2, const float* __restrict__ pw,
    _Float16* __restrict__ qkvx, _Float16* __restrict__ qkvc_h, _Float16* __restrict__ eb7,
    _Float16* __restrict__ w1h, _Float16* __restrict__ w2h, _Float16* __restrict__ pwh)
{
    __shared__ float sXf[4160];                     // 64 x 65 f32
    __shared__ alignas(16) _Float16 sOut[16512];    // 64 x 258 f16 ([192 qkv | 64 x | pad])
    const int t = threadIdx.x, bid = blockIdx.x;
    if (bid < 256) {
        const int p0 = bid*64;
        const int b = p0 >> 12, hw0 = p0 & 4095;
        for (int i = t; i < 4096; i += 1024) {
            int c = i >> 6, pp = i & 63;
            sXf[pp*65 + c] = x[(size_t)b*262144 + (size_t)c*4096 + hw0 + pp];
        }
        __syncthreads();
        // x -> f16 columns of the combined row
        for (int i = t; i < 2048; i += 1024) {
            int pp = i >> 5, j = i & 31;
            h2f v = h2f{(_Float16)sXf[pp*65 + 2*j], (_Float16)sXf[pp*65 + 2*j + 1]};
            __builtin_memcpy(sOut + pp*258 + 192 + 2*j, &v, 4);
        }
        const int pix = t & 63, g = t >> 6;
        float xr[64]; float s = 0.f, s2 = 0.f;
        #pragma unroll
        for (int c = 0; c < 64; ++c) { float v = sXf[pix*65 + c]; xr[c] = v; s += v; s2 += v*v; }
        float m = s*0.015625f;
        float rstd = rsqrtf(fmaxf(s2*0.015625f - m*m, 0.f) + 1e-5f);
        #pragma unroll
        for (int c = 0; c < 64; ++c) xr[c] = (xr[c] - m)*rstd*n1w[c] + n1b[c];
        #pragma unroll
        for (int i4 = 0; i4 < 12; i4 += 4) {
            const int o = g*12 + i4;                 // wave-uniform -> s_load weights
            const float* wr = qw + o*64;
            float a0 = qb[o], a1 = qb[o+1], a2 = qb[o+2], a3 = qb[o+3];
            #pragma unroll 16
            for (int c = 0; c < 64; ++c) {
                float xv = xr[c];
                a0 += xv*wr[c]; a1 += xv*wr[64+c]; a2 += xv*wr[128+c]; a3 += xv*wr[192+c];
            }
            pk4 pk;
            pk.h[0]=(_Float16)a0; pk.h[1]=(_Float16)a1; pk.h[2]=(_Float16)a2; pk.h[3]=(_Float16)a3;
            __builtin_memcpy(sOut + pix*258 + o, &pk, 8);
        }
        __syncthreads();
        // coalesced store: 64 rows x 32 float4 (256 f16/row)
        for (int i = t; i < 2048; i += 1024) {
            int pp = i >> 5, d4 = i & 31;
            ((float4*)qkvx)[(size_t)bid*2048 + i] = ld16(sOut + pp*258 + d4*8);
        }
        return;
    }
    if (bid < 264) {
        const int cid = bid - 256;
        for (int i = t; i < 4608; i += 1024) {
            int j = cid*4608 + i;
            if (j < 16384)      w1h[j]          = (_Float16)w1[j];
            else if (j < 32768) w2h[j - 16384]  = (_Float16)w2[j - 16384];
            else                pwh[j - 32768]  = (_Float16)pw[j - 32768];
        }
        return;
    }
    // setup: qkv_const = n1b @ qkv_w^T + qkv_b; 7-slot exp(bias) table
    if (t < 192) {
        float acc = qb[t];
        for (int c = 0; c < 64; ++c) acc += n1b[c]*qw[t*64 + c];
        qkvc_h[t] = (_Float16)acc;
    }
    for (int i = t; i < 3200; i += 1024) {
        int j = i & 7, hf = (i >> 3) & 1, r = i >> 4;   // r = h*25+q
        int h = r/25, q = r - h*25;
        float v = 0.f;
        if (j < 6) {
            int k = hf*6 + j;
            int ridx = (q/5 - k/5 + 4)*9 + (q%5 - k%5 + 4);
            v = __expf(rpb[ridx*8 + h]);
        } else if (j == 6 && hf) {
            for (int k = 12; k < 25; ++k) {
                int ridx = (q/5 - k/5 + 4)*9 + (q%5 - k%5 + 4);
                v += __expf(rpb[ridx*8 + h]);
            }
        }
        eb7[i] = (_Float16)v;
    }
}

// ---------------- K2: fused xsum + attention + LN2 + MLP + proj ----------------
// block = 512 thr, 32 pixels. Window 108 x 256 f16 (stride 258).
__global__ __launch_bounds__(512) void k_fused(
    const _Float16* __restrict__ qkvx, const _Float16* __restrict__ qkvc_h,
    const _Float16* __restrict__ eb7g,
    const float* __restrict__ n2w, const float* __restrict__ n2b,
    const float* __restrict__ b1, const float* __restrict__ b2, const float* __restrict__ pb,
    const _Float16* __restrict__ w1h, const _Float16* __restrict__ w2h, const _Float16* __restrict__ pwh,
    float* __restrict__ out)
{
    __shared__ alignas(16) char smem[70832];
    _Float16* sq   = (_Float16*)(smem);            // 108 x 258 f16 = 55728 B (attn phase)
    _Float16* seb  = (_Float16*)(smem + 55728);    // 3200 f16 = 6400 B
    _Float16* sqc  = (_Float16*)(smem + 62128);    // 192 f16 = 384 B
    float*    sOs  = (float*)   (smem + 62512);    // 32 x 65 f32 = 8320 B (whole kernel)
    // overlays inside dead sq after attention:
    _Float16* sH   = (_Float16*)(smem);            // 32 x 258 f16 = 16512 B
    h2f*      sAv  = (h2f*)     (smem + 16512);    // 32 x 34 = 4352 B
    float*    sRW  = (float*)   (smem + 20880);    // 8 x 33 x 2 f32 = 2112 B
    float*    sMR  = (float*)   (smem + 23008);    // 32 x 2 f32 = 256 B
    _Float16* sY   = (_Float16*)(smem + 55728);    // 32 x 74 f16 (over seb)

    const int t = threadIdx.x;
    const int p0 = blockIdx.x*32;
    const int b = p0 >> 12, hw0 = p0 & 4095, hrow = hw0 >> 6, w0c = hw0 & 63;

    // ---- phase 0: stage ----
    for (int i = t; i < 1600; i += 512) ((unsigned int*)seb)[i] = ((const unsigned int*)eb7g)[i];
    if (t < 96) ((unsigned int*)sqc)[t] = ((const unsigned int*)qkvc_h)[t];
    for (int i = t; i < 3456; i += 512) {
        int row = i >> 5, d4 = i & 31;
        int rr = row/36, cc = row%36;
        int gr = hrow - 2 + rr, gc = w0c - 2 + cc;
        float4 v;
        if (gr >= 0 && gc >= 0 && gc < 64)
            v = ((const float4*)qkvx)[((size_t)((b << 12) + (gr << 6) + gc))*32 + d4];
        else if (d4 < 24)
            v = ((const float4*)qkvc_h)[d4];
        else
            v = make_float4(0.f, 0.f, 0.f, 0.f);
        st16(sq + row*258 + d4*8, v);
    }
    __syncthreads();

    // ---- phase 1a: neighbor xsum from staged x columns -> sOs ----
    {
        const int pix = t & 31, sl = t >> 5;        // sl in [0,16)
        const int c4 = sl*4;
        float s0 = 0.f, s1 = 0.f, s2 = 0.f, s3 = 0.f;
        #pragma unroll
        for (int s = 0; s < 12; ++s) {
            const _Float16* xp = sq + ((s/5)*36 + pix + (s%5))*258 + 192 + c4;
            h2f a = ldh2(xp), bq = ldh2(xp + 2);
            s0 += (float)a.x; s1 += (float)a.y; s2 += (float)bq.x; s3 += (float)bq.y;
        }
        sOs[pix*65 + c4]     = s0;
        sOs[pix*65 + c4 + 1] = s1;
        sOs[pix*65 + c4 + 2] = s2;
        sOs[pix*65 + c4 + 3] = s3;
    }
    __syncthreads();

    // ---- phase 1b: attention (k-split halves, shfl_xor(32)) ----
    {
        const int pix = t & 31, hf = (t >> 5) & 1, h = t >> 6, hb = h*8;
        int rws[6];
        #pragma unroll
        for (int j = 0; j < 6; ++j) { int k = hf*6 + j; rws[j] = (k/5)*36 + pix + (k%5); }
        u8h kreg[7];
        #pragma unroll
        for (int j = 0; j < 6; ++j) kreg[j] = ldh8(sq + rws[j]*258 + 64 + hb);
        kreg[6] = hf ? ldh8(sqc + 64 + hb) : kreg[0];
        u8h qcu = ldh8(sqc + hb);
        float edc[7];
        #pragma unroll
        for (int j = 0; j < 7; ++j) edc[j] = __expf(dot8(qcu, kreg[j])*SC);
        float w[7];
        #pragma unroll
        for (int j = 0; j < 7; ++j) w[j] = 0.f;
        const _Float16* ebbase = seb + h*400 + hf*8;

        for (int sIdx = 0; sIdx < 12; ++sIdx) {
            int rq = (sIdx/5)*36 + pix + (sIdx%5);
            u8h qu = ldh8(sq + rq*258 + hb);
            h8 eb8; __builtin_memcpy(&eb8, ebbase + sIdx*16, 16);
            float e[7]; float rs = 0.f;
            #pragma unroll
            for (int j = 0; j < 7; ++j) {
                float ev = __expf(dot8(qu, kreg[j])*SC)*(float)eb8[j];
                e[j] = ev; rs += ev;
            }
            rs += __shfl_xor(rs, 32);
            float inv = frcp(rs);
            #pragma unroll
            for (int j = 0; j < 7; ++j) w[j] += e[j]*inv;
        }
        for (int q = 12; q < 25; ++q) {
            h8 eb8; __builtin_memcpy(&eb8, ebbase + q*16, 16);
            float e[7]; float rs = 0.f;
            #pragma unroll
            for (int j = 0; j < 7; ++j) {
                float ev = edc[j]*(float)eb8[j];
                e[j] = ev; rs += ev;
            }
            rs += __shfl_xor(rs, 32);
            float inv = frcp(rs);
            #pragma unroll
            for (int j = 0; j < 7; ++j) w[j] += e[j]*inv;
        }
        float o8[8];
        #pragma unroll
        for (int d = 0; d < 8; ++d) o8[d] = 0.f;
        #pragma unroll
        for (int j = 0; j < 7; ++j) {
            const _Float16* vp = (j < 6) ? (sq + rws[j]*258 + 128 + hb)
                                         : (hf ? sqc + 128 + hb : sq + rws[0]*258 + 128 + hb);
            u8h vv = ldh8(vp);
            float wj = w[j];
            #pragma unroll
            for (int d4 = 0; d4 < 4; ++d4) {
                h2f pr = vv.p[d4];
                o8[d4*2]   += wj*(float)pr.x;
                o8[d4*2+1] += wj*(float)pr.y;
            }
        }
        #pragma unroll
        for (int d = 0; d < 8; ++d) o8[d] += __shfl_xor(o8[d], 32);
        const int c0 = hb + hf*4;
        float* ap = sOs + pix*65 + c0;
        #pragma unroll
        for (int j = 0; j < 4; ++j) ap[j] += o8[hf*4 + j];
    }
    __syncthreads();   // sq/seb/sqc dead; sOs = out_sumed

    // ---- phase 2: LN2 ----
    const int pix = t & 31, sl = t >> 5;             // sl in [0,16)
    const int c4 = sl*4;
    float ps = 0.f, ps2 = 0.f;
    float vch[4];
    #pragma unroll
    for (int j = 0; j < 4; ++j) {
        float v = sOs[pix*65 + c4 + j];
        vch[j] = v; ps += v; ps2 += v*v;
    }
    ps  += __shfl_xor(ps, 32);
    ps2 += __shfl_xor(ps2, 32);
    const int wv = t >> 6;
    if (((t >> 5) & 1) == 0) {
        sRW[(wv*33 + pix)*2]     = ps;
        sRW[(wv*33 + pix)*2 + 1] = ps2;
    }
    __syncthreads();
    if (t < 32) {
        float s = 0.f, s2 = 0.f;
        #pragma unroll
        for (int g = 0; g < 8; ++g) { s += sRW[(g*33 + t)*2]; s2 += sRW[(g*33 + t)*2 + 1]; }
        float m = s*0.015625f;
        sMR[t*2]     = m;
        sMR[t*2 + 1] = rsqrtf(fmaxf(s2*0.015625f - m*m, 0.f) + 1e-5f);
    }
    __syncthreads();
    {
        float m = sMR[pix*2], r = sMR[pix*2 + 1];
        #pragma unroll
        for (int j = 0; j < 2; ++j) {
            float e0 = (vch[2*j]   - m)*r*n2w[c4 + 2*j]   + n2b[c4 + 2*j];
            float e1 = (vch[2*j+1] - m)*r*n2w[c4 + 2*j+1] + n2b[c4 + 2*j+1];
            sAv[pix*34 + sl*2 + j] = h2f{(_Float16)e0, (_Float16)e1};
        }
    }
    __syncthreads();

    // ---- phase 3: fc1 + GELU -> sH ----
    {
        const h2f* avr = sAv + pix*34;
        #pragma unroll
        for (int i4 = 0; i4 < 16; i4 += 4) {
            const int j = sl*16 + i4;
            const h2f* wr = (const h2f*)(w1h + (size_t)j*64);
            float a0 = b1[j], a1 = b1[j+1], a2 = b1[j+2], a3 = b1[j+3];
            #pragma unroll
            for (int cp = 0; cp < 32; ++cp) {
                h2f xv = avr[cp];
                a0 = fdot2f(xv, wr[cp],      a0);
                a1 = fdot2f(xv, wr[32 + cp], a1);
                a2 = fdot2f(xv, wr[64 + cp], a2);
                a3 = fdot2f(xv, wr[96 + cp], a3);
            }
            sH[pix*258 + j]     = (_Float16)(0.5f*a0*(1.f + erff(a0*0.70710678f)));
            sH[pix*258 + j + 1] = (_Float16)(0.5f*a1*(1.f + erff(a1*0.70710678f)));
            sH[pix*258 + j + 2] = (_Float16)(0.5f*a2*(1.f + erff(a2*0.70710678f)));
            sH[pix*258 + j + 3] = (_Float16)(0.5f*a3*(1.f + erff(a3*0.70710678f)));
        }
    }
    __syncthreads();

    // ---- phase 4: fc2 + residual -> sY ----
    {
        const int o = sl*4;
        const h2f* wr = (const h2f*)(w2h + (size_t)o*256);
        const h2f* hr = (const h2f*)(sH + pix*258);
        float a0 = b2[o], a1 = b2[o+1], a2 = b2[o+2], a3 = b2[o+3];
        #pragma unroll 32
        for (int jp = 0; jp < 128; ++jp) {
            h2f hv = hr[jp];
            a0 = fdot2f(hv, wr[jp],       a0);
            a1 = fdot2f(hv, wr[128 + jp], a1);
            a2 = fdot2f(hv, wr[256 + jp], a2);
            a3 = fdot2f(hv, wr[384 + jp], a3);
        }
        a0 += sOs[pix*65 + o];
        a1 += sOs[pix*65 + o + 1];
        a2 += sOs[pix*65 + o + 2];
        a3 += sOs[pix*65 + o + 3];
        sY[pix*74 + o]     = (_Float16)a0;
        sY[pix*74 + o + 1] = (_Float16)a1;
        sY[pix*74 + o + 2] = (_Float16)a2;
        sY[pix*74 + o + 3] = (_Float16)a3;
    }
    __syncthreads();

    // ---- phase 5: proj -> out ----
    {
        const int o = sl*4;
        const h2f* wr = (const h2f*)(pwh + (size_t)o*64);
        const h2f* yr = (const h2f*)(sY + pix*74);
        float a0 = pb[o], a1 = pb[o+1], a2 = pb[o+2], a3 = pb[o+3];
        #pragma unroll
        for (int cp = 0; cp < 32; ++cp) {
            h2f yv = yr[cp];
            a0 = fdot2f(yv, wr[cp],      a0);
            a1 = fdot2f(yv, wr[32 + cp], a1);
            a2 = fdot2f(yv, wr[64 + cp], a2);
            a3 = fdot2f(yv, wr[96 + cp], a3);
        }
        const int p = p0 + pix;
        const int bimg = p >> 12, hw = p & 4095, hh = hw >> 6, ww = hw & 63;
        float* ob = out + ((size_t)((bimg*64 + o)*64 + hh))*64 + ww;
        ob[0]     = a0;
        ob[4096]  = a1;
        ob[8192]  = a2;
        ob[12288] = a3;
    }
}

extern "C" void kernel_launch(void* const* d_in, const int* in_sizes, int n_in,
                              void* d_out, int out_size, void* d_ws, size_t ws_size,
                              hipStream_t stream) {
    const float* x   = (const float*)d_in[0];
    const float* n1w = (const float*)d_in[1];
    const float* n1b = (const float*)d_in[2];
    const float* qw  = (const float*)d_in[3];
    const float* qb  = (const float*)d_in[4];
    const float* rpb = (const float*)d_in[5];
    const float* n2w = (const float*)d_in[6];
    const float* n2b = (const float*)d_in[7];
    const float* w1  = (const float*)d_in[8];
    const float* b1  = (const float*)d_in[9];
    const float* w2  = (const float*)d_in[10];
    const float* b2  = (const float*)d_in[11];
    const float* pw  = (const float*)d_in[12];
    const float* pb  = (const float*)d_in[13];
    float* out = (float*)d_out;

    float* ws = (float*)d_ws;
    _Float16* qkvx   = (_Float16*)ws;              // 16384*256 f16 = 2,097,152 floats
    _Float16* qkvc_h = (_Float16*)(ws + 2097152);  // 192 f16 (96 floats)
    _Float16* eb7    = (_Float16*)(ws + 2097248);  // 3200 f16 (1600 floats)
    _Float16* w1h    = (_Float16*)(ws + 2098848);  // 16384 f16 (8192)
    _Float16* w2h    = (_Float16*)(ws + 2107040);  // 16384 f16 (8192)
    _Float16* pwh    = (_Float16*)(ws + 2115232);  // 4096 f16 (2048) -> ~8.5 MB total

    hipLaunchKernelGGL(k_qkv, dim3(265), dim3(1024), 0, stream,
                       x, n1w, n1b, qw, qb, rpb, w1, w2, pw,
                       qkvx, qkvc_h, eb7, w1h, w2h, pwh);
    hipLaunchKernelGGL(k_fused, dim3(512), dim3(512), 0, stream,
                       qkvx, qkvc_h, eb7,
                       n2w, n2b, b1, b2, pb, w1h, w2h, pwh, out);
}